// Round 2
// baseline (390.059 us; speedup 1.0000x reference)
//
#include <hip/hip_runtime.h>
#include <hip/hip_bf16.h>

typedef __attribute__((ext_vector_type(8))) short s8v;   // 8 x bf16 bits
typedef __attribute__((ext_vector_type(4))) short s4v;
typedef __attribute__((ext_vector_type(4))) float f4v;

#define B_   8
#define T_   4096
#define C_   1024
#define HS_  64
#define K2_  2048

__device__ __forceinline__ int keep_of(int i) {
    // keep[i] for i in [0,2048): exact integer version of the reference formula
    if (i >= 1024) return 2048 + i;
    int d = 1023 - i;
    return 3071 - ((3 * d * d + 1023) >> 10);
}

__device__ __forceinline__ short bf16_bits(float f) {
    union { __hip_bfloat16 h; short s; } u;
    u.h = __float2bfloat16(f);
    return u.s;
}

// load 8 consecutive fp32, round to bf16, pack into an MFMA bf16 fragment half
__device__ __forceinline__ s8v cvt8f(const float* p) {
    const f4v a = *(const f4v*)p;
    const f4v b = *(const f4v*)(p + 4);
    s8v r;
    r[0] = bf16_bits(a[0]); r[1] = bf16_bits(a[1]);
    r[2] = bf16_bits(a[2]); r[3] = bf16_bits(a[3]);
    r[4] = bf16_bits(b[0]); r[5] = bf16_bits(b[1]);
    r[6] = bf16_bits(b[2]); r[7] = bf16_bits(b[3]);
    return r;
}

// ---------------- Kernel A: fused QKV projection ----------------------------
// x:(B*T, C) fp32 -> Qo:(B*T,64), Ko:(B*T,64), Vt:(B,64,T)  all bf16 in ws.
// wave w owns output columns [16w,16w+16) of q/k/v, 4 m-tiles x 3 n-tiles.
__global__ __launch_bounds__(256, 2) void qkv_kernel(
    const float* __restrict__ x,
    const float* __restrict__ Wq, const float* __restrict__ bq,
    const float* __restrict__ Wk, const float* __restrict__ bk,
    const float* __restrict__ Wv, const float* __restrict__ bv,
    __hip_bfloat16* __restrict__ Qo, __hip_bfloat16* __restrict__ Ko,
    __hip_bfloat16* __restrict__ Vt)
{
    const int wave = threadIdx.x >> 6;
    const int lane = threadIdx.x & 63;
    const int l16  = lane & 15;
    const int quad = lane >> 4;
    const int row0 = blockIdx.x * 64;
    const int wrow = wave * 16 + l16;      // W row == output column (0..63)

    f4v acc[4][3];
    #pragma unroll
    for (int i = 0; i < 4; ++i)
        #pragma unroll
        for (int j = 0; j < 3; ++j) {
            acc[i][j][0] = 0.f; acc[i][j][1] = 0.f;
            acc[i][j][2] = 0.f; acc[i][j][3] = 0.f;
        }

    const float* wq_p = Wq + (size_t)wrow * C_ + quad * 8;
    const float* wk_p = Wk + (size_t)wrow * C_ + quad * 8;
    const float* wv_p = Wv + (size_t)wrow * C_ + quad * 8;
    const float* x_p  = x + (size_t)(row0 + l16) * C_ + quad * 8;

    for (int k0 = 0; k0 < C_; k0 += 32) {
        s8v bq_f = cvt8f(wq_p + k0);
        s8v bk_f = cvt8f(wk_p + k0);
        s8v bv_f = cvt8f(wv_p + k0);
        #pragma unroll
        for (int mt = 0; mt < 4; ++mt) {
            s8v afr = cvt8f(x_p + (size_t)mt * 16 * C_ + k0);
            acc[mt][0] = __builtin_amdgcn_mfma_f32_16x16x32_bf16(afr, bq_f, acc[mt][0], 0, 0, 0);
            acc[mt][1] = __builtin_amdgcn_mfma_f32_16x16x32_bf16(afr, bk_f, acc[mt][1], 0, 0, 0);
            acc[mt][2] = __builtin_amdgcn_mfma_f32_16x16x32_bf16(afr, bv_f, acc[mt][2], 0, 0, 0);
        }
    }

    const float bqv = bq[wrow];
    const float bkv = bk[wrow];
    const float bvv = bv[wrow];

    // C/D layout: col = lane&15, row = quad*4+reg
    #pragma unroll
    for (int mt = 0; mt < 4; ++mt) {
        const int rbase = row0 + mt * 16 + quad * 4;   // global token row
        #pragma unroll
        for (int r = 0; r < 4; ++r) {
            Qo[(size_t)(rbase + r) * HS_ + wrow] = __float2bfloat16(acc[mt][0][r] + bqv);
            Ko[(size_t)(rbase + r) * HS_ + wrow] = __float2bfloat16(acc[mt][1][r] + bkv);
        }
        s4v vp;
        #pragma unroll
        for (int r = 0; r < 4; ++r) vp[r] = bf16_bits(acc[mt][2][r] + bvv);
        const int bb = rbase >> 12;          // batch
        const int tt = rbase & (T_ - 1);     // token within batch (block never crosses b)
        *(s4v*)(Vt + ((size_t)(bb * HS_ + wrow)) * T_ + tt) = vp;   // 8B packed store
    }
}

// ---------------- Kernel B: flash attention over kept queries ---------------
// WG = 64 kept-query rows of one batch; wave w owns rows [16w,16w+16).
// t-loop over 64-wide K/V tiles staged in LDS (XOR-swizzled 16B chunks).
__global__ __launch_bounds__(256) void attn_kernel(
    const __hip_bfloat16* __restrict__ Qo,
    const __hip_bfloat16* __restrict__ Ko,
    const __hip_bfloat16* __restrict__ Vt,
    float* __restrict__ out)
{
    __shared__ __align__(16) short kt[64 * 64];      // [t][d] swizzled
    __shared__ __align__(16) short vt[64 * 64];      // [d][t] swizzled
    __shared__ __align__(16) short pt[4][16 * 64];   // per-wave P, [m][t] swizzled

    const int b    = blockIdx.x >> 5;
    const int qb   = blockIdx.x & 31;
    const int wave = threadIdx.x >> 6;
    const int lane = threadIdx.x & 63;
    const int l16  = lane & 15;
    const int quad = lane >> 4;
    const int tid  = threadIdx.x;

    // Q fragments (A-operand): m = lane&15, k = quad*8+j ; gather via keep[]
    const int qi = qb * 64 + wave * 16 + l16;
    const int qt = keep_of(qi);
    const __hip_bfloat16* qrow = Qo + ((size_t)(b * T_ + qt)) * HS_;
    const s8v aq0 = *(const s8v*)(qrow + quad * 8);
    const s8v aq1 = *(const s8v*)(qrow + 32 + quad * 8);

    int keepr[4];
    #pragma unroll
    for (int r = 0; r < 4; ++r) keepr[r] = keep_of(qb * 64 + wave * 16 + quad * 4 + r);

    const int tmax  = keep_of(qb * 64 + 63);   // keep[] ascending -> WG max
    const int niter = (tmax >> 6) + 1;

    f4v accO[4];
    #pragma unroll
    for (int j = 0; j < 4; ++j) { accO[j][0]=0.f; accO[j][1]=0.f; accO[j][2]=0.f; accO[j][3]=0.f; }
    float m_i[4] = {-1e30f, -1e30f, -1e30f, -1e30f};
    float l_i[4] = {0.f, 0.f, 0.f, 0.f};

    const int srow = tid >> 3;   // staging row 0..31
    const int sc   = tid & 7;    // staging 16B-chunk 0..7
    short* pw = pt[wave];

    for (int it = 0; it < niter; ++it) {
        const int t0 = it << 6;
        __syncthreads();
        #pragma unroll
        for (int j = 0; j < 2; ++j) {
            const int row = srow + 32 * j;
            const int p   = sc ^ (row & 7);          // bank-conflict-free swizzle
            *(s8v*)(kt + row * 64 + p * 8) =
                *(const s8v*)(Ko + ((size_t)(b * T_ + t0 + row)) * HS_ + sc * 8);
            *(s8v*)(vt + row * 64 + p * 8) =
                *(const s8v*)(Vt + ((size_t)(b * HS_ + row)) * T_ + t0 + sc * 8);
        }
        __syncthreads();

        // S = Q K^T  (B-operand: n = t = lane&15 + 16*jn, k = d)
        f4v s[4];
        #pragma unroll
        for (int jn = 0; jn < 4; ++jn) {
            const int trow = jn * 16 + l16;
            const s8v bk0 = *(const s8v*)(kt + trow * 64 + ((quad    ) ^ (trow & 7)) * 8);
            const s8v bk1 = *(const s8v*)(kt + trow * 64 + ((quad + 4) ^ (trow & 7)) * 8);
            f4v z; z[0]=0.f; z[1]=0.f; z[2]=0.f; z[3]=0.f;
            z = __builtin_amdgcn_mfma_f32_16x16x32_bf16(aq0, bk0, z, 0, 0, 0);
            z = __builtin_amdgcn_mfma_f32_16x16x32_bf16(aq1, bk1, z, 0, 0, 0);
            s[jn] = z;
        }

        // scale + mask: valid iff t_global <= keep[row]
        #pragma unroll
        for (int jn = 0; jn < 4; ++jn) {
            const int tg = t0 + jn * 16 + l16;
            #pragma unroll
            for (int r = 0; r < 4; ++r) {
                float v = s[jn][r] * 0.03125f;       // C^-0.5 = 1/32
                s[jn][r] = (tg <= keepr[r]) ? v : -1e30f;
            }
        }

        // online softmax: rows live at (quad*4+r), cols at lane&15 -> 16-lane butterfly
        f4v tmx = s[0];
        #pragma unroll
        for (int jn = 1; jn < 4; ++jn)
            #pragma unroll
            for (int r = 0; r < 4; ++r) tmx[r] = fmaxf(tmx[r], s[jn][r]);
        #pragma unroll
        for (int off = 1; off < 16; off <<= 1)
            #pragma unroll
            for (int r = 0; r < 4; ++r) tmx[r] = fmaxf(tmx[r], __shfl_xor(tmx[r], off));

        float alpha[4];
        #pragma unroll
        for (int r = 0; r < 4; ++r) {
            const float mn = fmaxf(m_i[r], tmx[r]);
            alpha[r] = __expf(m_i[r] - mn);
            m_i[r] = mn;
        }
        f4v rs; rs[0]=0.f; rs[1]=0.f; rs[2]=0.f; rs[3]=0.f;
        #pragma unroll
        for (int jn = 0; jn < 4; ++jn)
            #pragma unroll
            for (int r = 0; r < 4; ++r) {
                const float p = __expf(s[jn][r] - m_i[r]);
                s[jn][r] = p;
                rs[r] += p;
            }
        #pragma unroll
        for (int off = 1; off < 16; off <<= 1)
            #pragma unroll
            for (int r = 0; r < 4; ++r) rs[r] += __shfl_xor(rs[r], off);
        #pragma unroll
        for (int r = 0; r < 4; ++r) l_i[r] = l_i[r] * alpha[r] + rs[r];
        #pragma unroll
        for (int jd = 0; jd < 4; ++jd)
            #pragma unroll
            for (int r = 0; r < 4; ++r) accO[jd][r] *= alpha[r];

        // P: C-layout -> LDS (bf16, swizzled) -> A-layout. Wave-private; DS ops
        // from one wave complete in order, so no barrier needed.
        #pragma unroll
        for (int jn = 0; jn < 4; ++jn) {
            const int t = jn * 16 + l16;
            const int chunk = t >> 3;
            #pragma unroll
            for (int r = 0; r < 4; ++r) {
                const int m = quad * 4 + r;
                const int p = chunk ^ (m & 7);
                pw[m * 64 + p * 8 + (t & 7)] = bf16_bits(s[jn][r]);
            }
        }
        const s8v ap0 = *(const s8v*)(pw + l16 * 64 + ((quad    ) ^ (l16 & 7)) * 8);
        const s8v ap1 = *(const s8v*)(pw + l16 * 64 + ((quad + 4) ^ (l16 & 7)) * 8);

        // O += P V  (B-operand from Vt: n = d, k = t)
        #pragma unroll
        for (int jd = 0; jd < 4; ++jd) {
            const int drow = jd * 16 + l16;
            const s8v bv0 = *(const s8v*)(vt + drow * 64 + ((quad    ) ^ (drow & 7)) * 8);
            const s8v bv1 = *(const s8v*)(vt + drow * 64 + ((quad + 4) ^ (drow & 7)) * 8);
            accO[jd] = __builtin_amdgcn_mfma_f32_16x16x32_bf16(ap0, bv0, accO[jd], 0, 0, 0);
            accO[jd] = __builtin_amdgcn_mfma_f32_16x16x32_bf16(ap1, bv1, accO[jd], 0, 0, 0);
        }
    }

    #pragma unroll
    for (int r = 0; r < 4; ++r) {
        const float inv = 1.0f / l_i[r];
        const int io = qb * 64 + wave * 16 + quad * 4 + r;   // kept-row index
        #pragma unroll
        for (int jd = 0; jd < 4; ++jd)
            out[((size_t)(b * K2_ + io)) * HS_ + jd * 16 + l16] =
                accO[jd][r] * inv;
    }
}

extern "C" void kernel_launch(void* const* d_in, const int* in_sizes, int n_in,
                              void* d_out, int out_size, void* d_ws, size_t ws_size,
                              hipStream_t stream) {
    (void)in_sizes; (void)n_in; (void)out_size; (void)ws_size;
    const float* x  = (const float*)d_in[0];
    const float* Wq = (const float*)d_in[1];
    const float* bq = (const float*)d_in[2];
    const float* Wk = (const float*)d_in[3];
    const float* bk = (const float*)d_in[4];
    const float* Wv = (const float*)d_in[5];
    const float* bv = (const float*)d_in[6];

    __hip_bfloat16* Qo = (__hip_bfloat16*)d_ws;                       // 4 MB
    __hip_bfloat16* Ko = Qo + (size_t)B_ * T_ * HS_;                  // 4 MB
    __hip_bfloat16* Vt = Ko + (size_t)B_ * T_ * HS_;                  // 4 MB
    float* o = (float*)d_out;

    qkv_kernel<<<dim3((B_ * T_) / 64), dim3(256), 0, stream>>>(
        x, Wq, bq, Wk, bk, Wv, bv, Qo, Ko, Vt);
    attn_kernel<<<dim3(B_ * (K2_ / 64)), dim3(256), 0, stream>>>(Qo, Ko, Vt, o);
}

// Round 3
// 355.161 us; speedup vs baseline: 1.0983x; 1.0983x over previous
//
#include <hip/hip_runtime.h>
#include <hip/hip_bf16.h>

typedef __attribute__((ext_vector_type(8))) short s8v;   // 8 x bf16 bits
typedef __attribute__((ext_vector_type(4))) short s4v;
typedef __attribute__((ext_vector_type(4))) float f4v;

#define B_   8
#define T_   4096
#define C_   1024
#define HS_  64
#define K2_  2048

__device__ __forceinline__ int keep_of(int i) {
    // keep[i] for i in [0,2048): exact integer version of the reference formula
    if (i >= 1024) return 2048 + i;
    int d = 1023 - i;
    return 3071 - ((3 * d * d + 1023) >> 10);
}

__device__ __forceinline__ short bf16_bits(float f) {
    union { __hip_bfloat16 h; short s; } u;
    u.h = __float2bfloat16(f);
    return u.s;
}

// load 8 consecutive fp32, round to bf16, pack into an MFMA bf16 fragment half
__device__ __forceinline__ s8v cvt8f(const float* p) {
    const f4v a = *(const f4v*)p;
    const f4v b = *(const f4v*)(p + 4);
    s8v r;
    r[0] = bf16_bits(a[0]); r[1] = bf16_bits(a[1]);
    r[2] = bf16_bits(a[2]); r[3] = bf16_bits(a[3]);
    r[4] = bf16_bits(b[0]); r[5] = bf16_bits(b[1]);
    r[6] = bf16_bits(b[2]); r[7] = bf16_bits(b[3]);
    return r;
}

// ---------------- Kernel A: fused QKV projection ----------------------------
// x:(B*T, C) fp32 -> Qo:(B*T,64), Ko:(B*T,64), Vt:(B,64,T) all bf16 in ws.
// x is converted fp32->bf16 ONCE per block into LDS (v1 converted 4x, one per
// wave). Wave w owns output cols [16w,16w+16) of q/k/v; W read direct (L2-hot).
__global__ __launch_bounds__(256, 2) void qkv_kernel(
    const float* __restrict__ x,
    const float* __restrict__ Wq, const float* __restrict__ bq,
    const float* __restrict__ Wk, const float* __restrict__ bk,
    const float* __restrict__ Wv, const float* __restrict__ bv,
    __hip_bfloat16* __restrict__ Qo, __hip_bfloat16* __restrict__ Ko,
    __hip_bfloat16* __restrict__ Vt)
{
    __shared__ __align__(16) short xs[64 * 64];   // [row][k] swizzled, 8KB

    const int tid  = threadIdx.x;
    const int wave = tid >> 6;
    const int lane = tid & 63;
    const int l16  = lane & 15;
    const int quad = lane >> 4;
    const int row0 = blockIdx.x * 64;
    const int wrow = wave * 16 + l16;      // W row == output column (0..63)

    f4v acc[4][3];
    #pragma unroll
    for (int i = 0; i < 4; ++i)
        #pragma unroll
        for (int j = 0; j < 3; ++j) {
            acc[i][j][0] = 0.f; acc[i][j][1] = 0.f;
            acc[i][j][2] = 0.f; acc[i][j][3] = 0.f;
        }

    const float* wq_p = Wq + (size_t)wrow * C_;
    const float* wk_p = Wk + (size_t)wrow * C_;
    const float* wv_p = Wv + (size_t)wrow * C_;

    const int   srow = tid >> 2;                       // staging row 0..63
    const int   sc0  = (tid & 3) * 2;                  // chunk pair base 0/2/4/6
    const float* xg  = x + (size_t)(row0 + srow) * C_ + (tid & 3) * 16;
    short* xrow = xs + srow * 64;

    for (int k0 = 0; k0 < C_; k0 += 64) {
        // global loads issued before the barrier -> overlap previous compute
        s8v v0 = cvt8f(xg + k0);
        s8v v1 = cvt8f(xg + k0 + 8);
        __syncthreads();                               // prev reads done
        *(s8v*)(xrow + ((sc0    ) ^ (srow & 7)) * 8) = v0;
        *(s8v*)(xrow + ((sc0 + 1) ^ (srow & 7)) * 8) = v1;
        __syncthreads();
        #pragma unroll
        for (int kk = 0; kk < 64; kk += 32) {
            s8v bqf = cvt8f(wq_p + k0 + kk + quad * 8);
            s8v bkf = cvt8f(wk_p + k0 + kk + quad * 8);
            s8v bvf = cvt8f(wv_p + k0 + kk + quad * 8);
            const int c = (kk >> 3) + quad;
            #pragma unroll
            for (int mt = 0; mt < 4; ++mt) {
                const int r = mt * 16 + l16;
                s8v afr = *(const s8v*)(xs + r * 64 + (c ^ (r & 7)) * 8);
                acc[mt][0] = __builtin_amdgcn_mfma_f32_16x16x32_bf16(afr, bqf, acc[mt][0], 0, 0, 0);
                acc[mt][1] = __builtin_amdgcn_mfma_f32_16x16x32_bf16(afr, bkf, acc[mt][1], 0, 0, 0);
                acc[mt][2] = __builtin_amdgcn_mfma_f32_16x16x32_bf16(afr, bvf, acc[mt][2], 0, 0, 0);
            }
        }
    }

    const float bqv = bq[wrow];
    const float bkv = bk[wrow];
    const float bvv = bv[wrow];

    // C/D layout: col = lane&15, row = quad*4+reg
    #pragma unroll
    for (int mt = 0; mt < 4; ++mt) {
        const int rbase = row0 + mt * 16 + quad * 4;   // global token row
        #pragma unroll
        for (int r = 0; r < 4; ++r) {
            Qo[(size_t)(rbase + r) * HS_ + wrow] = __float2bfloat16(acc[mt][0][r] + bqv);
            Ko[(size_t)(rbase + r) * HS_ + wrow] = __float2bfloat16(acc[mt][1][r] + bkv);
        }
        s4v vp;
        #pragma unroll
        for (int r = 0; r < 4; ++r) vp[r] = bf16_bits(acc[mt][2][r] + bvv);
        const int bb = rbase >> 12;          // batch
        const int tt = rbase & (T_ - 1);     // token within batch
        *(s4v*)(Vt + ((size_t)(bb * HS_ + wrow)) * T_ + tt) = vp;   // 8B store
    }
}

// ---------------- Kernel B: flash attention over kept queries ---------------
// Block = 16 kept-query rows of one batch; the 4 waves SPLIT THE t-DIMENSION
// (wave w takes tile w of each staged 256-wide K/V group), with a final
// cross-wave online-softmax merge through LDS. b = blockIdx&7 -> one batch
// per XCD, K/V L2-resident.
__global__ __launch_bounds__(256, 2) void attn_kernel(
    const __hip_bfloat16* __restrict__ Qo,
    const __hip_bfloat16* __restrict__ Ko,
    const __hip_bfloat16* __restrict__ Vt,
    float* __restrict__ out)
{
    __shared__ __align__(16) char smem[65536];        // 64KB exactly
    short* kt = (short*)smem;                         // [256][64] swizzled 32KB
    short* vs = (short*)(smem + 32768);               // [64][256] swizzled 32KB
    // merge overlay (used only after the loop): mM[64], mL[64], mO[4][16][64]
    float* mM = (float*)smem;
    float* mL = (float*)(smem + 256);
    float* mO = (float*)(smem + 512);

    const int b    = blockIdx.x & 7;                  // XCD-affine batch
    const int qb   = blockIdx.x >> 3;                 // q-tile 0..127
    const int tid  = threadIdx.x;
    const int wave = tid >> 6;
    const int lane = tid & 63;
    const int l16  = lane & 15;
    const int quad = lane >> 4;

    // Q fragments (A-operand): m = lane&15, k = quad*8+j ; gather via keep[]
    const int qt = keep_of(qb * 16 + l16);
    const __hip_bfloat16* qrow = Qo + ((size_t)(b * T_ + qt)) * HS_;
    const s8v aq0 = *(const s8v*)(qrow + quad * 8);
    const s8v aq1 = *(const s8v*)(qrow + 32 + quad * 8);

    int keepr[4];
    #pragma unroll
    for (int r = 0; r < 4; ++r) keepr[r] = keep_of(qb * 16 + quad * 4 + r);

    const int tmax = keep_of(qb * 16 + 15);           // keep[] ascending
    const int ng   = (tmax >> 8) + 1;                 // 256-wide groups

    f4v accO[4];
    #pragma unroll
    for (int j = 0; j < 4; ++j) { accO[j][0]=0.f; accO[j][1]=0.f; accO[j][2]=0.f; accO[j][3]=0.f; }
    float m_i[4] = {-1e30f, -1e30f, -1e30f, -1e30f};
    float l_i[4] = {0.f, 0.f, 0.f, 0.f};

    // wave-private P buffer overlaid on this wave's own (dead-by-then) K slice;
    // kt swizzle for row (wave*64+m) == pt swizzle for row m since 64w%8==0.
    short* pw = kt + wave * 64 * 64;

    const int vd = tid >> 2;                          // V staging: d row 0..63
    const int vc = (tid & 3) * 8;                     // chunk base (of 32)

    for (int g = 0; g < ng; ++g) {
        // ---- cooperative staging of 256 t-rows of K and V ----
        {
            const int tr = g * 256 + tid;             // K row (always < T)
            const __hip_bfloat16* kg = Ko + ((size_t)(b * T_ + tr)) * HS_;
            short* krow = kt + tid * 64;
            #pragma unroll
            for (int c = 0; c < 8; ++c)
                *(s8v*)(krow + (c ^ (tid & 7)) * 8) = *(const s8v*)(kg + c * 8);
            const __hip_bfloat16* vg = Vt + ((size_t)(b * HS_ + vd)) * T_ + g * 256;
            short* vrow = vs + vd * 256;
            #pragma unroll
            for (int j = 0; j < 8; ++j) {
                const int c = vc + j;
                *(s8v*)(vrow + (c ^ (vd & 7)) * 8) = *(const s8v*)(vg + c * 8);
            }
        }
        __syncthreads();

        const int t0 = g * 256 + wave * 64;           // this wave's tile
        if (t0 <= tmax) {
            // S = Q K^T  (B-operand: n = local t, k = d)
            f4v s[4];
            #pragma unroll
            for (int jn = 0; jn < 4; ++jn) {
                const int trow = wave * 64 + jn * 16 + l16;
                const s8v bk0 = *(const s8v*)(kt + trow * 64 + ((quad    ) ^ (trow & 7)) * 8);
                const s8v bk1 = *(const s8v*)(kt + trow * 64 + ((quad + 4) ^ (trow & 7)) * 8);
                f4v z; z[0]=0.f; z[1]=0.f; z[2]=0.f; z[3]=0.f;
                z = __builtin_amdgcn_mfma_f32_16x16x32_bf16(aq0, bk0, z, 0, 0, 0);
                z = __builtin_amdgcn_mfma_f32_16x16x32_bf16(aq1, bk1, z, 0, 0, 0);
                s[jn] = z;
            }

            // scale + mask: valid iff t_global <= keep[row]
            #pragma unroll
            for (int jn = 0; jn < 4; ++jn) {
                const int tg = t0 + jn * 16 + l16;
                #pragma unroll
                for (int r = 0; r < 4; ++r) {
                    float v = s[jn][r] * 0.03125f;    // C^-0.5 = 1/32
                    s[jn][r] = (tg <= keepr[r]) ? v : -1e30f;
                }
            }

            // online softmax (rows at quad*4+r, cols at lane&15)
            f4v tmx = s[0];
            #pragma unroll
            for (int jn = 1; jn < 4; ++jn)
                #pragma unroll
                for (int r = 0; r < 4; ++r) tmx[r] = fmaxf(tmx[r], s[jn][r]);
            #pragma unroll
            for (int off = 1; off < 16; off <<= 1)
                #pragma unroll
                for (int r = 0; r < 4; ++r) tmx[r] = fmaxf(tmx[r], __shfl_xor(tmx[r], off));

            float alpha[4];
            #pragma unroll
            for (int r = 0; r < 4; ++r) {
                const float mn = fmaxf(m_i[r], tmx[r]);
                alpha[r] = __expf(m_i[r] - mn);
                m_i[r] = mn;
            }
            f4v rs; rs[0]=0.f; rs[1]=0.f; rs[2]=0.f; rs[3]=0.f;
            #pragma unroll
            for (int jn = 0; jn < 4; ++jn)
                #pragma unroll
                for (int r = 0; r < 4; ++r) {
                    const float p = __expf(s[jn][r] - m_i[r]);
                    s[jn][r] = p;
                    rs[r] += p;
                }
            #pragma unroll
            for (int off = 1; off < 16; off <<= 1)
                #pragma unroll
                for (int r = 0; r < 4; ++r) rs[r] += __shfl_xor(rs[r], off);
            #pragma unroll
            for (int r = 0; r < 4; ++r) l_i[r] = l_i[r] * alpha[r] + rs[r];
            #pragma unroll
            for (int jd = 0; jd < 4; ++jd)
                #pragma unroll
                for (int r = 0; r < 4; ++r) accO[jd][r] *= alpha[r];

            // P: C-layout -> LDS -> A-layout (wave-private slice, DS in-order)
            #pragma unroll
            for (int jn = 0; jn < 4; ++jn) {
                const int t = jn * 16 + l16;
                const int chunk = t >> 3;
                #pragma unroll
                for (int r = 0; r < 4; ++r) {
                    const int m = quad * 4 + r;
                    const int p = chunk ^ (m & 7);
                    pw[m * 64 + p * 8 + (t & 7)] = bf16_bits(s[jn][r]);
                }
            }
            const s8v ap0 = *(const s8v*)(pw + l16 * 64 + ((quad    ) ^ (l16 & 7)) * 8);
            const s8v ap1 = *(const s8v*)(pw + l16 * 64 + ((quad + 4) ^ (l16 & 7)) * 8);

            // O += P V  (B-operand: n = d, k = local t within wave's 64 cols)
            #pragma unroll
            for (int jd = 0; jd < 4; ++jd) {
                const int d = jd * 16 + l16;
                const int c0 = wave * 8 + quad;
                const s8v bv0 = *(const s8v*)(vs + d * 256 + ((c0    ) ^ (d & 7)) * 8);
                const s8v bv1 = *(const s8v*)(vs + d * 256 + ((c0 + 4) ^ (d & 7)) * 8);
                accO[jd] = __builtin_amdgcn_mfma_f32_16x16x32_bf16(ap0, bv0, accO[jd], 0, 0, 0);
                accO[jd] = __builtin_amdgcn_mfma_f32_16x16x32_bf16(ap1, bv1, accO[jd], 0, 0, 0);
            }
        }
        __syncthreads();                              // before next staging
    }

    // ---- cross-wave merge of online-softmax state (LDS overlay) ----
    #pragma unroll
    for (int r = 0; r < 4; ++r) {
        const int row = quad * 4 + r;
        if (l16 == 0) {
            mM[wave * 16 + row] = m_i[r];
            mL[wave * 16 + row] = l_i[r];
        }
        #pragma unroll
        for (int jd = 0; jd < 4; ++jd)
            mO[wave * 1024 + row * 64 + jd * 16 + l16] = accO[jd][r];
    }
    __syncthreads();

    {
        const int row = tid >> 4;                     // 0..15
        const int col = (tid & 15) * 4;               // 0..60
        float M = mM[row];
        #pragma unroll
        for (int w = 1; w < 4; ++w) M = fmaxf(M, mM[w * 16 + row]);
        float L = 0.f;
        float cw[4];
        #pragma unroll
        for (int w = 0; w < 4; ++w) {
            cw[w] = __expf(mM[w * 16 + row] - M);
            L += cw[w] * mL[w * 16 + row];
        }
        f4v o; o[0]=0.f; o[1]=0.f; o[2]=0.f; o[3]=0.f;
        #pragma unroll
        for (int w = 0; w < 4; ++w) {
            const f4v ow = *(const f4v*)(mO + w * 1024 + row * 64 + col);
            #pragma unroll
            for (int j = 0; j < 4; ++j) o[j] += cw[w] * ow[j];
        }
        const float inv = 1.0f / L;
        #pragma unroll
        for (int j = 0; j < 4; ++j) o[j] *= inv;
        *(f4v*)(out + ((size_t)(b * K2_ + qb * 16 + row)) * HS_ + col) = o;
    }
}

extern "C" void kernel_launch(void* const* d_in, const int* in_sizes, int n_in,
                              void* d_out, int out_size, void* d_ws, size_t ws_size,
                              hipStream_t stream) {
    (void)in_sizes; (void)n_in; (void)out_size; (void)ws_size;
    const float* x  = (const float*)d_in[0];
    const float* Wq = (const float*)d_in[1];
    const float* bq = (const float*)d_in[2];
    const float* Wk = (const float*)d_in[3];
    const float* bk = (const float*)d_in[4];
    const float* Wv = (const float*)d_in[5];
    const float* bv = (const float*)d_in[6];

    __hip_bfloat16* Qo = (__hip_bfloat16*)d_ws;                       // 4 MB
    __hip_bfloat16* Ko = Qo + (size_t)B_ * T_ * HS_;                  // 4 MB
    __hip_bfloat16* Vt = Ko + (size_t)B_ * T_ * HS_;                  // 4 MB
    float* o = (float*)d_out;

    qkv_kernel<<<dim3((B_ * T_) / 64), dim3(256), 0, stream>>>(
        x, Wq, bq, Wk, bk, Wv, bv, Qo, Ko, Vt);
    attn_kernel<<<dim3(B_ * (K2_ / 16)), dim3(256), 0, stream>>>(Qo, Ko, Vt, o);
}

// Round 4
// 308.705 us; speedup vs baseline: 1.2635x; 1.1505x over previous
//
#include <hip/hip_runtime.h>
#include <hip/hip_bf16.h>

typedef __attribute__((ext_vector_type(8))) short s8v;   // 8 x bf16 bits
typedef __attribute__((ext_vector_type(4))) short s4v;
typedef __attribute__((ext_vector_type(4))) float f4v;

#define B_   8
#define T_   4096
#define C_   1024
#define HS_  64
#define K2_  2048

__device__ __forceinline__ int keep_of(int i) {
    // keep[i] for i in [0,2048): exact integer version of the reference formula
    if (i >= 1024) return 2048 + i;
    int d = 1023 - i;
    return 3071 - ((3 * d * d + 1023) >> 10);
}

__device__ __forceinline__ short bf16_bits(float f) {
    union { __hip_bfloat16 h; short s; } u;
    u.h = __float2bfloat16(f);
    return u.s;
}

// load 8 consecutive fp32, round to bf16, pack into an MFMA bf16 fragment half
__device__ __forceinline__ s8v cvt8f(const float* p) {
    const f4v a = *(const f4v*)p;
    const f4v b = *(const f4v*)(p + 4);
    s8v r;
    r[0] = bf16_bits(a[0]); r[1] = bf16_bits(a[1]);
    r[2] = bf16_bits(a[2]); r[3] = bf16_bits(a[3]);
    r[4] = bf16_bits(b[0]); r[5] = bf16_bits(b[1]);
    r[6] = bf16_bits(b[2]); r[7] = bf16_bits(b[3]);
    return r;
}

// ------------- Kernel W: one-shot fp32 -> bf16 conversion of Wq/Wk/Wv -------
__global__ __launch_bounds__(256) void wcvt_kernel(
    const float* __restrict__ Wq, const float* __restrict__ Wk,
    const float* __restrict__ Wv, short* __restrict__ Wb)
{
    const int idx = (blockIdx.x * 256 + threadIdx.x) * 8;   // 0..196600
    const int mat = idx >> 16;                              // 0,1,2
    const int off = idx & 65535;
    const float* src = (mat == 0) ? Wq : (mat == 1) ? Wk : Wv;
    *(s8v*)(Wb + idx) = cvt8f(src + off);
}

// ---------------- Kernel A: fused QKV projection ----------------------------
// x:(B*T, C) fp32 -> Qo:(B*T,64), Ko:(B*T,64), Vt:(B,64,T) all bf16 in ws.
// x converted fp32->bf16 once per block into LDS; W read as bf16 (pre-pass).
__global__ __launch_bounds__(256, 2) void qkv_kernel(
    const float* __restrict__ x,
    const short* __restrict__ Wb,
    const float* __restrict__ bq, const float* __restrict__ bk,
    const float* __restrict__ bv,
    __hip_bfloat16* __restrict__ Qo, __hip_bfloat16* __restrict__ Ko,
    __hip_bfloat16* __restrict__ Vt)
{
    __shared__ __align__(16) short xs[64 * 64];   // [row][k] swizzled, 8KB

    const int tid  = threadIdx.x;
    const int wave = tid >> 6;
    const int lane = tid & 63;
    const int l16  = lane & 15;
    const int quad = lane >> 4;
    const int row0 = blockIdx.x * 64;
    const int wrow = wave * 16 + l16;      // W row == output column (0..63)

    f4v acc[4][3];
    #pragma unroll
    for (int i = 0; i < 4; ++i)
        #pragma unroll
        for (int j = 0; j < 3; ++j) {
            acc[i][j][0] = 0.f; acc[i][j][1] = 0.f;
            acc[i][j][2] = 0.f; acc[i][j][3] = 0.f;
        }

    const short* wq_p = Wb + (size_t)wrow * C_ + quad * 8;
    const short* wk_p = Wb + 65536 + (size_t)wrow * C_ + quad * 8;
    const short* wv_p = Wb + 131072 + (size_t)wrow * C_ + quad * 8;

    const int   srow = tid >> 2;                       // staging row 0..63
    const int   sc0  = (tid & 3) * 2;                  // chunk pair base
    const float* xg  = x + (size_t)(row0 + srow) * C_ + (tid & 3) * 16;
    short* xrow = xs + srow * 64;

    for (int k0 = 0; k0 < C_; k0 += 64) {
        s8v v0 = cvt8f(xg + k0);
        s8v v1 = cvt8f(xg + k0 + 8);
        __syncthreads();                               // prev reads done
        *(s8v*)(xrow + ((sc0    ) ^ (srow & 7)) * 8) = v0;
        *(s8v*)(xrow + ((sc0 + 1) ^ (srow & 7)) * 8) = v1;
        __syncthreads();
        #pragma unroll
        for (int kk = 0; kk < 64; kk += 32) {
            s8v bqf = *(const s8v*)(wq_p + k0 + kk);
            s8v bkf = *(const s8v*)(wk_p + k0 + kk);
            s8v bvf = *(const s8v*)(wv_p + k0 + kk);
            const int c = (kk >> 3) + quad;
            #pragma unroll
            for (int mt = 0; mt < 4; ++mt) {
                const int r = mt * 16 + l16;
                s8v afr = *(const s8v*)(xs + r * 64 + (c ^ (r & 7)) * 8);
                acc[mt][0] = __builtin_amdgcn_mfma_f32_16x16x32_bf16(afr, bqf, acc[mt][0], 0, 0, 0);
                acc[mt][1] = __builtin_amdgcn_mfma_f32_16x16x32_bf16(afr, bkf, acc[mt][1], 0, 0, 0);
                acc[mt][2] = __builtin_amdgcn_mfma_f32_16x16x32_bf16(afr, bvf, acc[mt][2], 0, 0, 0);
            }
        }
    }

    const float bqv = bq[wrow];
    const float bkv = bk[wrow];
    const float bvv = bv[wrow];

    // C/D layout: col = lane&15, row = quad*4+reg
    #pragma unroll
    for (int mt = 0; mt < 4; ++mt) {
        const int rbase = row0 + mt * 16 + quad * 4;   // global token row
        #pragma unroll
        for (int r = 0; r < 4; ++r) {
            Qo[(size_t)(rbase + r) * HS_ + wrow] = __float2bfloat16(acc[mt][0][r] + bqv);
            Ko[(size_t)(rbase + r) * HS_ + wrow] = __float2bfloat16(acc[mt][1][r] + bkv);
        }
        s4v vp;
        #pragma unroll
        for (int r = 0; r < 4; ++r) vp[r] = bf16_bits(acc[mt][2][r] + bvv);
        const int bb = rbase >> 12;          // batch
        const int tt = rbase & (T_ - 1);     // token within batch
        *(s4v*)(Vt + ((size_t)(bb * HS_ + wrow)) * T_ + tt) = vp;   // 8B store
    }
}

// ---------------- Kernel B: flash attention over kept queries ---------------
// Block = 16 kept-q rows; 4 waves split t (wave w takes 64-t tiles w, w+4, ..)
// K/V fragments read DIRECTLY from global (L2-resident per XCD) -> no in-loop
// barriers, waves fully independent. LDS only for wave-private P transform
// and the final cross-wave softmax merge.
__global__ __launch_bounds__(256) void attn_kernel(
    const __hip_bfloat16* __restrict__ Qo,
    const __hip_bfloat16* __restrict__ Ko,
    const __hip_bfloat16* __restrict__ Vt,
    float* __restrict__ out)
{
    __shared__ __align__(16) char smem[17408];
    // phase 1: per-wave P buffers (4 x 16x64 shorts = 8KB)
    // phase 2 (after barrier): mM[64], mL[64] floats + mO[4][16][64] floats
    float* mM = (float*)smem;
    float* mL = (float*)(smem + 256);
    float* mO = (float*)(smem + 512);

    const int b    = blockIdx.x & 7;                  // XCD-affine batch
    const int qb   = blockIdx.x >> 3;                 // q-tile 0..127
    const int tid  = threadIdx.x;
    const int wave = tid >> 6;
    const int lane = tid & 63;
    const int l16  = lane & 15;
    const int quad = lane >> 4;

    short* pw = (short*)smem + wave * 1024;           // wave-private P

    // Q fragments (A-operand): m = lane&15, k = quad*8+j ; gather via keep[]
    const int qt = keep_of(qb * 16 + l16);
    const __hip_bfloat16* qrow = Qo + ((size_t)(b * T_ + qt)) * HS_;
    const s8v aq0 = *(const s8v*)(qrow + quad * 8);
    const s8v aq1 = *(const s8v*)(qrow + 32 + quad * 8);

    int keepr[4];
    #pragma unroll
    for (int r = 0; r < 4; ++r) keepr[r] = keep_of(qb * 16 + quad * 4 + r);

    const int tmax   = keep_of(qb * 16 + 15);         // keep[] ascending
    const int ntiles = (tmax >> 6) + 1;               // 64-wide t tiles

    f4v accO[4];
    #pragma unroll
    for (int j = 0; j < 4; ++j) { accO[j][0]=0.f; accO[j][1]=0.f; accO[j][2]=0.f; accO[j][3]=0.f; }
    float m_i[4] = {-1e30f, -1e30f, -1e30f, -1e30f};
    float l_i[4] = {0.f, 0.f, 0.f, 0.f};

    const __hip_bfloat16* kbase = Ko + (size_t)b * T_ * HS_;
    const __hip_bfloat16* vbase = Vt + (size_t)b * HS_ * T_;

    for (int tt = wave; tt < ntiles; tt += 4) {
        const int t0 = tt << 6;

        // ---- V fragments (prefetch early; B-operand: n=d, k=t) ----
        s8v bv0[4], bv1[4];
        #pragma unroll
        for (int jd = 0; jd < 4; ++jd) {
            const __hip_bfloat16* vr = vbase + (size_t)(jd * 16 + l16) * T_ + t0 + quad * 8;
            bv0[jd] = *(const s8v*)(vr);
            bv1[jd] = *(const s8v*)(vr + 32);
        }

        // ---- S = Q K^T (B-operand: n = t, k = d; 16B contiguous rows) ----
        f4v s[4];
        #pragma unroll
        for (int jn = 0; jn < 4; ++jn) {
            const __hip_bfloat16* kr = kbase + (size_t)(t0 + jn * 16 + l16) * HS_ + quad * 8;
            const s8v bk0 = *(const s8v*)(kr);
            const s8v bk1 = *(const s8v*)(kr + 32);
            f4v z; z[0]=0.f; z[1]=0.f; z[2]=0.f; z[3]=0.f;
            z = __builtin_amdgcn_mfma_f32_16x16x32_bf16(aq0, bk0, z, 0, 0, 0);
            z = __builtin_amdgcn_mfma_f32_16x16x32_bf16(aq1, bk1, z, 0, 0, 0);
            s[jn] = z;
        }

        // scale + mask: valid iff t_global <= keep[row]
        #pragma unroll
        for (int jn = 0; jn < 4; ++jn) {
            const int tg = t0 + jn * 16 + l16;
            #pragma unroll
            for (int r = 0; r < 4; ++r) {
                float v = s[jn][r] * 0.03125f;        // C^-0.5 = 1/32
                s[jn][r] = (tg <= keepr[r]) ? v : -1e30f;
            }
        }

        // online softmax (rows at quad*4+r, cols at lane&15)
        f4v tmx = s[0];
        #pragma unroll
        for (int jn = 1; jn < 4; ++jn)
            #pragma unroll
            for (int r = 0; r < 4; ++r) tmx[r] = fmaxf(tmx[r], s[jn][r]);
        #pragma unroll
        for (int off = 1; off < 16; off <<= 1)
            #pragma unroll
            for (int r = 0; r < 4; ++r) tmx[r] = fmaxf(tmx[r], __shfl_xor(tmx[r], off));

        float alpha[4];
        #pragma unroll
        for (int r = 0; r < 4; ++r) {
            const float mn = fmaxf(m_i[r], tmx[r]);
            alpha[r] = __expf(m_i[r] - mn);
            m_i[r] = mn;
        }
        f4v rs; rs[0]=0.f; rs[1]=0.f; rs[2]=0.f; rs[3]=0.f;
        #pragma unroll
        for (int jn = 0; jn < 4; ++jn)
            #pragma unroll
            for (int r = 0; r < 4; ++r) {
                const float p = __expf(s[jn][r] - m_i[r]);
                s[jn][r] = p;
                rs[r] += p;
            }
        #pragma unroll
        for (int off = 1; off < 16; off <<= 1)
            #pragma unroll
            for (int r = 0; r < 4; ++r) rs[r] += __shfl_xor(rs[r], off);
        #pragma unroll
        for (int r = 0; r < 4; ++r) l_i[r] = l_i[r] * alpha[r] + rs[r];
        #pragma unroll
        for (int jd = 0; jd < 4; ++jd)
            #pragma unroll
            for (int r = 0; r < 4; ++r) accO[jd][r] *= alpha[r];

        // P: C-layout -> LDS -> A-layout (wave-private slice, DS in-order)
        #pragma unroll
        for (int jn = 0; jn < 4; ++jn) {
            const int t = jn * 16 + l16;
            const int chunk = t >> 3;
            #pragma unroll
            for (int r = 0; r < 4; ++r) {
                const int m = quad * 4 + r;
                const int p = chunk ^ (m & 7);
                pw[m * 64 + p * 8 + (t & 7)] = bf16_bits(s[jn][r]);
            }
        }
        const s8v ap0 = *(const s8v*)(pw + l16 * 64 + ((quad    ) ^ (l16 & 7)) * 8);
        const s8v ap1 = *(const s8v*)(pw + l16 * 64 + ((quad + 4) ^ (l16 & 7)) * 8);

        // O += P V
        #pragma unroll
        for (int jd = 0; jd < 4; ++jd) {
            accO[jd] = __builtin_amdgcn_mfma_f32_16x16x32_bf16(ap0, bv0[jd], accO[jd], 0, 0, 0);
            accO[jd] = __builtin_amdgcn_mfma_f32_16x16x32_bf16(ap1, bv1[jd], accO[jd], 0, 0, 0);
        }
    }

    // ---- cross-wave merge of online-softmax state ----
    __syncthreads();                                  // pt buffers now dead
    #pragma unroll
    for (int r = 0; r < 4; ++r) {
        const int row = quad * 4 + r;
        if (l16 == 0) {
            mM[wave * 16 + row] = m_i[r];
            mL[wave * 16 + row] = l_i[r];
        }
        #pragma unroll
        for (int jd = 0; jd < 4; ++jd)
            mO[wave * 1024 + row * 64 + jd * 16 + l16] = accO[jd][r];
    }
    __syncthreads();

    {
        const int row = tid >> 4;                     // 0..15
        const int col = (tid & 15) * 4;               // 0..60
        float M = mM[row];
        #pragma unroll
        for (int w = 1; w < 4; ++w) M = fmaxf(M, mM[w * 16 + row]);
        float L = 0.f;
        float cw[4];
        #pragma unroll
        for (int w = 0; w < 4; ++w) {
            cw[w] = __expf(mM[w * 16 + row] - M);     // 0 for no-data waves
            L += cw[w] * mL[w * 16 + row];
        }
        f4v o; o[0]=0.f; o[1]=0.f; o[2]=0.f; o[3]=0.f;
        #pragma unroll
        for (int w = 0; w < 4; ++w) {
            const f4v ow = *(const f4v*)(mO + w * 1024 + row * 64 + col);
            #pragma unroll
            for (int j = 0; j < 4; ++j) o[j] += cw[w] * ow[j];
        }
        const float inv = 1.0f / L;
        #pragma unroll
        for (int j = 0; j < 4; ++j) o[j] *= inv;
        *(f4v*)(out + ((size_t)(b * K2_ + qb * 16 + row)) * HS_ + col) = o;
    }
}

extern "C" void kernel_launch(void* const* d_in, const int* in_sizes, int n_in,
                              void* d_out, int out_size, void* d_ws, size_t ws_size,
                              hipStream_t stream) {
    (void)in_sizes; (void)n_in; (void)out_size; (void)ws_size;
    const float* x  = (const float*)d_in[0];
    const float* Wq = (const float*)d_in[1];
    const float* bq = (const float*)d_in[2];
    const float* Wk = (const float*)d_in[3];
    const float* bk = (const float*)d_in[4];
    const float* Wv = (const float*)d_in[5];
    const float* bv = (const float*)d_in[6];

    __hip_bfloat16* Qo = (__hip_bfloat16*)d_ws;                       // 4 MB
    __hip_bfloat16* Ko = Qo + (size_t)B_ * T_ * HS_;                  // 4 MB
    __hip_bfloat16* Vt = Ko + (size_t)B_ * T_ * HS_;                  // 4 MB
    short*          Wb = (short*)(Vt + (size_t)B_ * HS_ * T_);        // 384 KB
    float* o = (float*)d_out;

    wcvt_kernel<<<dim3(96), dim3(256), 0, stream>>>(Wq, Wk, Wv, Wb);
    qkv_kernel<<<dim3((B_ * T_) / 64), dim3(256), 0, stream>>>(
        x, Wb, bq, bk, bv, Qo, Ko, Vt);
    attn_kernel<<<dim3(B_ * (K2_ / 16)), dim3(256), 0, stream>>>(Qo, Ko, Vt, o);
}